// Round 4
// baseline (48.133 us; speedup 1.0000x reference)
//
#include <hip/hip_runtime.h>
#include <math.h>

#define NACC 24
#define GRID1 2048

// acc layout (canonical 24-vector):
//  0: lt count          (dbp_pred < sbp_pred)
//  1: sum_d   2: sum_d2   3: sum_dp  4: sum_dp2
//  5: sum_s   6: sum_s2   7: sum_sp  8: sum_sp2
//  9,12,15,18,21: mask counts
// 10,13,16,19,22: mask . smape_d
// 11,14,17,20,23: mask . smape_s

// f32 per-thread accumulation is safe: each thread sees only 8 elements, so
// per-thread partials carry ~1e-7 relative error; promoted to f64 before any
// cross-thread summation. Worst-case on the variance numerator ~6e-6 rel,
// threshold is 2.5e-3.
__device__ __forceinline__ void process_elem(float* acc, int* cnt,
                                             float dpv, float spv, float dv, float sv) {
    cnt[0] += (dpv < spv) ? 1 : 0;
    acc[0] += dv;  acc[1] = fmaf(dv,  dv,  acc[1]);
    acc[2] += dpv; acc[3] = fmaf(dpv, dpv, acc[3]);
    acc[4] += sv;  acc[5] = fmaf(sv,  sv,  acc[5]);
    acc[6] += spv; acc[7] = fmaf(spv, spv, acc[7]);
    float smd = 2.0f * fabsf(dpv - dv) * __builtin_amdgcn_rcpf(fabsf(dpv) + fabsf(dv));
    float sms = 2.0f * fabsf(spv - sv) * __builtin_amdgcn_rcpf(fabsf(spv) + fabsf(sv));
    // mask precedence: & binds tighter than | in the reference
    bool m0 = (sv < 120.0f) && (dv < 80.0f);
    bool m1 = (sv >= 120.0f) && (sv < 130.0f) && (dv < 80.0f);
    bool m2 = ((sv >= 130.0f) && (sv < 140.0f)) || ((dv >= 80.0f) && (dv < 90.0f));
    bool m3 = (sv >= 140.0f) || (dv >= 90.0f);
    bool m4 = (sv > 180.0f) || (dv > 120.0f);
    cnt[1] += m0 ? 1 : 0;  acc[8]  += m0 ? smd : 0.0f;  acc[9]  += m0 ? sms : 0.0f;
    cnt[2] += m1 ? 1 : 0;  acc[10] += m1 ? smd : 0.0f;  acc[11] += m1 ? sms : 0.0f;
    cnt[3] += m2 ? 1 : 0;  acc[12] += m2 ? smd : 0.0f;  acc[13] += m2 ? sms : 0.0f;
    cnt[4] += m3 ? 1 : 0;  acc[14] += m3 ? smd : 0.0f;  acc[15] += m3 ? sms : 0.0f;
    cnt[5] += m4 ? 1 : 0;  acc[16] += m4 ? smd : 0.0f;  acc[17] += m4 ? sms : 0.0f;
}

__global__ __launch_bounds__(256) void amp_reduce(
    const float* __restrict__ dp, const float* __restrict__ sp,
    const float* __restrict__ d,  const float* __restrict__ s,
    double* __restrict__ partial, int n)
{
    float accF[18];
    int   accI[6];
    #pragma unroll
    for (int k = 0; k < 18; ++k) accF[k] = 0.0f;
    #pragma unroll
    for (int k = 0; k < 6; ++k) accI[k] = 0;

    const int tid = blockIdx.x * blockDim.x + threadIdx.x;
    const int stride = gridDim.x * blockDim.x;
    const int n4 = n >> 2;

    const float4* dp4 = (const float4*)dp;
    const float4* sp4 = (const float4*)sp;
    const float4* d4  = (const float4*)d;
    const float4* s4  = (const float4*)s;

    for (int i = tid; i < n4; i += stride) {
        float4 vdp = dp4[i];
        float4 vsp = sp4[i];
        float4 vd  = d4[i];
        float4 vs  = s4[i];
        process_elem(accF, accI, vdp.x, vsp.x, vd.x, vs.x);
        process_elem(accF, accI, vdp.y, vsp.y, vd.y, vs.y);
        process_elem(accF, accI, vdp.z, vsp.z, vd.z, vs.z);
        process_elem(accF, accI, vdp.w, vsp.w, vd.w, vs.w);
    }
    for (int i = (n4 << 2) + tid; i < n; i += stride) {
        process_elem(accF, accI, dp[i], sp[i], d[i], s[i]);
    }

    // promote to f64, assemble canonical 24-vector
    double acc[NACC];
    acc[0] = (double)accI[0];
    #pragma unroll
    for (int k = 0; k < 8; ++k) acc[1 + k] = (double)accF[k];
    #pragma unroll
    for (int g = 0; g < 5; ++g) {
        acc[9 + 3 * g]  = (double)accI[1 + g];
        acc[10 + 3 * g] = (double)accF[8 + 2 * g];
        acc[11 + 3 * g] = (double)accF[9 + 2 * g];
    }

    // block reduction in f64: wave shuffle -> LDS -> per-block slot (NO atomics)
    __shared__ double part[4][NACC];
    const int lane = threadIdx.x & 63;
    const int wave = threadIdx.x >> 6;
    #pragma unroll
    for (int k = 0; k < NACC; ++k) {
        double v = acc[k];
        #pragma unroll
        for (int off = 32; off > 0; off >>= 1)
            v += __shfl_down(v, off, 64);
        if (lane == 0) part[wave][k] = v;
    }
    __syncthreads();
    if (threadIdx.x < NACC) {
        double v = part[0][threadIdx.x] + part[1][threadIdx.x]
                 + part[2][threadIdx.x] + part[3][threadIdx.x];
        // transposed layout: column k contiguous over blocks -> coalesced stage-2 reads
        partial[threadIdx.x * GRID1 + blockIdx.x] = v;
    }
}

// 1024 threads = 16 waves. Wave w reduces columns {w, w+16}; full unroll with
// 4 independent accumulators so loads pipeline (one latency exposure/column).
__global__ __launch_bounds__(1024) void amp_final(
    const double* __restrict__ partial, float* __restrict__ out, int n)
{
    __shared__ double tot[NACC];
    const int lane = threadIdx.x & 63;
    const int wave = threadIdx.x >> 6;

    for (int k = wave; k < NACC; k += 16) {
        const double* col = partial + k * GRID1 + lane;
        double v0 = 0.0, v1 = 0.0, v2 = 0.0, v3 = 0.0;
        #pragma unroll
        for (int r = 0; r < GRID1 / 64; r += 4) {
            v0 += col[(r + 0) * 64];
            v1 += col[(r + 1) * 64];
            v2 += col[(r + 2) * 64];
            v3 += col[(r + 3) * 64];
        }
        double v = (v0 + v1) + (v2 + v3);
        #pragma unroll
        for (int off = 32; off > 0; off >>= 1)
            v += __shfl_down(v, off, 64);
        if (lane == 0) tot[k] = v;
    }
    __syncthreads();

    if (threadIdx.x == 0) {
        const double nf = (double)n;
        const double lt = tot[0];
        const double sum_d  = tot[1], sum_d2  = tot[2];
        const double sum_dp = tot[3], sum_dp2 = tot[4];
        const double sum_s  = tot[5], sum_s2  = tot[6];
        const double sum_sp = tot[7], sum_sp2 = tot[8];

        double scale_cost = 1.0 - lt / nf;

        double d_rst = 0.0, s_rst = 0.0, rst_d = 0.0, rst_s = 0.0;
        int cnt = 0;
        #pragma unroll
        for (int i = 0; i < 5; ++i) {
            double c   = tot[9 + 3 * i];
            double sdi = tot[10 + 3 * i];
            double ssi = tot[11 + 3 * i];
            double safe = fmax(c, 1.0);
            double w = sqrt(log(nf / safe));
            double sum_di = w * sdi;
            double sum_si = w * ssi;
            bool has = c > 0.0;
            double nd = (d_rst + sum_di) / safe;
            double ns = (s_rst + sum_si) / safe;
            if (has) {
                d_rst = nd; s_rst = ns;
                rst_d += nd; rst_s += ns;
                cnt++;
            }
        }
        double denom = (cnt == 0) ? 5.0 : (double)cnt;
        rst_d /= denom;
        rst_s /= denom;

        double mean_d  = sum_d / nf,  mean_dp = sum_dp / nf;
        double mean_s  = sum_s / nf,  mean_sp = sum_sp / nf;
        double var_d  = (sum_d2  - nf * mean_d  * mean_d)  / (nf - 1.0);
        double var_dp = (sum_dp2 - nf * mean_dp * mean_dp) / (nf - 1.0);
        double var_s  = (sum_s2  - nf * mean_s  * mean_s)  / (nf - 1.0);
        double var_sp = (sum_sp2 - nf * mean_sp * mean_sp) / (nf - 1.0);

        double dbp_mean_cost = fabs(mean_d - mean_dp) / mean_d;
        double sbp_mean_cost = fabs(mean_s - mean_sp) / mean_s;
        double dbp_var_cost  = fabs(var_d - var_dp) / var_d;
        double sbp_var_cost  = fabs(var_s - var_sp) / var_s;

        out[0] = (float)(rst_d + dbp_mean_cost + dbp_var_cost);
        out[1] = (float)(rst_s + sbp_mean_cost + sbp_var_cost);
        out[2] = (float)scale_cost;
    }
}

extern "C" void kernel_launch(void* const* d_in, const int* in_sizes, int n_in,
                              void* d_out, int out_size, void* d_ws, size_t ws_size,
                              hipStream_t stream) {
    const float* dp = (const float*)d_in[0];   // dbp_pred
    const float* sp = (const float*)d_in[1];   // sbp_pred
    // d_in[2] = mbp_pred (unused), d_in[5] = m (unused)
    const float* d  = (const float*)d_in[3];
    const float* s  = (const float*)d_in[4];
    const int n = in_sizes[0];

    double* partial = (double*)d_ws;           // NACC * GRID1 doubles = 384 KiB
    float* out = (float*)d_out;

    hipLaunchKernelGGL(amp_reduce, dim3(GRID1), dim3(256), 0, stream,
                       dp, sp, d, s, partial, n);
    hipLaunchKernelGGL(amp_final, dim3(1), dim3(1024), 0, stream,
                       partial, out, n);
}

// Round 5
// 47.175 us; speedup vs baseline: 1.0203x; 1.0203x over previous
//
#include <hip/hip_runtime.h>
#include <math.h>

#define NACC 24
#define GRID1 2048

// acc layout (canonical 24-vector):
//  0: lt count          (dbp_pred < sbp_pred)
//  1: sum_d   2: sum_d2   3: sum_dp  4: sum_dp2
//  5: sum_s   6: sum_s2   7: sum_sp  8: sum_sp2
//  9,12,15,18,21: mask counts
// 10,13,16,19,22: mask . smape_d
// 11,14,17,20,23: mask . smape_s

// f32 per-thread accumulation: 8 elements/thread -> ~1e-7 relative error,
// promoted to f64 before any cross-thread summation.
__device__ __forceinline__ void process_elem(float* acc, int* cnt,
                                             float dpv, float spv, float dv, float sv) {
    cnt[0] += (dpv < spv) ? 1 : 0;
    acc[0] += dv;  acc[1] = fmaf(dv,  dv,  acc[1]);
    acc[2] += dpv; acc[3] = fmaf(dpv, dpv, acc[3]);
    acc[4] += sv;  acc[5] = fmaf(sv,  sv,  acc[5]);
    acc[6] += spv; acc[7] = fmaf(spv, spv, acc[7]);
    float smd = 2.0f * fabsf(dpv - dv) * __builtin_amdgcn_rcpf(fabsf(dpv) + fabsf(dv));
    float sms = 2.0f * fabsf(spv - sv) * __builtin_amdgcn_rcpf(fabsf(spv) + fabsf(sv));
    // mask precedence: & binds tighter than | in the reference
    bool m0 = (sv < 120.0f) && (dv < 80.0f);
    bool m1 = (sv >= 120.0f) && (sv < 130.0f) && (dv < 80.0f);
    bool m2 = ((sv >= 130.0f) && (sv < 140.0f)) || ((dv >= 80.0f) && (dv < 90.0f));
    bool m3 = (sv >= 140.0f) || (dv >= 90.0f);
    bool m4 = (sv > 180.0f) || (dv > 120.0f);
    cnt[1] += m0 ? 1 : 0;  acc[8]  += m0 ? smd : 0.0f;  acc[9]  += m0 ? sms : 0.0f;
    cnt[2] += m1 ? 1 : 0;  acc[10] += m1 ? smd : 0.0f;  acc[11] += m1 ? sms : 0.0f;
    cnt[3] += m2 ? 1 : 0;  acc[12] += m2 ? smd : 0.0f;  acc[13] += m2 ? sms : 0.0f;
    cnt[4] += m3 ? 1 : 0;  acc[14] += m3 ? smd : 0.0f;  acc[15] += m3 ? sms : 0.0f;
    cnt[5] += m4 ? 1 : 0;  acc[16] += m4 ? smd : 0.0f;  acc[17] += m4 ? sms : 0.0f;
}

__device__ __forceinline__ void process4(float* acc, int* cnt,
                                         float4 vdp, float4 vsp, float4 vd, float4 vs) {
    process_elem(acc, cnt, vdp.x, vsp.x, vd.x, vs.x);
    process_elem(acc, cnt, vdp.y, vsp.y, vd.y, vs.y);
    process_elem(acc, cnt, vdp.z, vsp.z, vd.z, vs.z);
    process_elem(acc, cnt, vdp.w, vsp.w, vd.w, vs.w);
}

// One-shot: each thread owns exactly 2 float4 per array (8 elements).
// ALL 8 loads are issued before any arithmetic -> 8 KB in flight per wave.
__global__ __launch_bounds__(256) void amp_reduce(
    const float* __restrict__ dp, const float* __restrict__ sp,
    const float* __restrict__ d,  const float* __restrict__ s,
    double* __restrict__ partial, int n)
{
    const int n4 = n >> 2;
    const int i0 = blockIdx.x * 512 + threadIdx.x;   // float4 index, group 0
    const int i1 = i0 + 256;                          // float4 index, group 1

    const float4* dp4 = (const float4*)dp;
    const float4* sp4 = (const float4*)sp;
    const float4* d4  = (const float4*)d;
    const float4* s4  = (const float4*)s;

    const float4 z4 = make_float4(0.f, 0.f, 0.f, 0.f);
    const bool p0 = i0 < n4;
    const bool p1 = i1 < n4;

    // issue all 8 independent loads up front
    float4 a_dp0 = p0 ? dp4[i0] : z4;
    float4 a_sp0 = p0 ? sp4[i0] : z4;
    float4 a_d0  = p0 ? d4[i0]  : z4;
    float4 a_s0  = p0 ? s4[i0]  : z4;
    float4 a_dp1 = p1 ? dp4[i1] : z4;
    float4 a_sp1 = p1 ? sp4[i1] : z4;
    float4 a_d1  = p1 ? d4[i1]  : z4;
    float4 a_s1  = p1 ? s4[i1]  : z4;

    float accF[18];
    int   accI[6];
    #pragma unroll
    for (int k = 0; k < 18; ++k) accF[k] = 0.0f;
    #pragma unroll
    for (int k = 0; k < 6; ++k) accI[k] = 0;

    if (p0) process4(accF, accI, a_dp0, a_sp0, a_d0, a_s0);
    if (p1) process4(accF, accI, a_dp1, a_sp1, a_d1, a_s1);

    // promote to f64, assemble canonical 24-vector
    double acc[NACC];
    acc[0] = (double)accI[0];
    #pragma unroll
    for (int k = 0; k < 8; ++k) acc[1 + k] = (double)accF[k];
    #pragma unroll
    for (int g = 0; g < 5; ++g) {
        acc[9 + 3 * g]  = (double)accI[1 + g];
        acc[10 + 3 * g] = (double)accF[8 + 2 * g];
        acc[11 + 3 * g] = (double)accF[9 + 2 * g];
    }

    // block reduction in f64: wave shuffle -> LDS -> per-block slot (NO atomics)
    __shared__ double part[4][NACC];
    const int lane = threadIdx.x & 63;
    const int wave = threadIdx.x >> 6;
    #pragma unroll
    for (int k = 0; k < NACC; ++k) {
        double v = acc[k];
        #pragma unroll
        for (int off = 32; off > 0; off >>= 1)
            v += __shfl_down(v, off, 64);
        if (lane == 0) part[wave][k] = v;
    }
    __syncthreads();
    if (threadIdx.x < NACC) {
        double v = part[0][threadIdx.x] + part[1][threadIdx.x]
                 + part[2][threadIdx.x] + part[3][threadIdx.x];
        partial[threadIdx.x * GRID1 + blockIdx.x] = v;
    }
}

// 1024 threads = 16 waves. Wave w reduces columns {w, w+16}; unrolled with
// 4 independent accumulators so loads pipeline.
__global__ __launch_bounds__(1024) void amp_final(
    const double* __restrict__ partial, float* __restrict__ out, int n)
{
    __shared__ double tot[NACC];
    const int lane = threadIdx.x & 63;
    const int wave = threadIdx.x >> 6;

    for (int k = wave; k < NACC; k += 16) {
        const double* col = partial + k * GRID1 + lane;
        double v0 = 0.0, v1 = 0.0, v2 = 0.0, v3 = 0.0;
        #pragma unroll
        for (int r = 0; r < GRID1 / 64; r += 4) {
            v0 += col[(r + 0) * 64];
            v1 += col[(r + 1) * 64];
            v2 += col[(r + 2) * 64];
            v3 += col[(r + 3) * 64];
        }
        double v = (v0 + v1) + (v2 + v3);
        #pragma unroll
        for (int off = 32; off > 0; off >>= 1)
            v += __shfl_down(v, off, 64);
        if (lane == 0) tot[k] = v;
    }
    __syncthreads();

    if (threadIdx.x == 0) {
        const double nf = (double)n;
        const double lt = tot[0];
        const double sum_d  = tot[1], sum_d2  = tot[2];
        const double sum_dp = tot[3], sum_dp2 = tot[4];
        const double sum_s  = tot[5], sum_s2  = tot[6];
        const double sum_sp = tot[7], sum_sp2 = tot[8];

        double scale_cost = 1.0 - lt / nf;

        double d_rst = 0.0, s_rst = 0.0, rst_d = 0.0, rst_s = 0.0;
        int cnt = 0;
        #pragma unroll
        for (int i = 0; i < 5; ++i) {
            double c   = tot[9 + 3 * i];
            double sdi = tot[10 + 3 * i];
            double ssi = tot[11 + 3 * i];
            double safe = fmax(c, 1.0);
            double w = sqrt(log(nf / safe));
            double sum_di = w * sdi;
            double sum_si = w * ssi;
            bool has = c > 0.0;
            double nd = (d_rst + sum_di) / safe;
            double ns = (s_rst + sum_si) / safe;
            if (has) {
                d_rst = nd; s_rst = ns;
                rst_d += nd; rst_s += ns;
                cnt++;
            }
        }
        double denom = (cnt == 0) ? 5.0 : (double)cnt;
        rst_d /= denom;
        rst_s /= denom;

        double mean_d  = sum_d / nf,  mean_dp = sum_dp / nf;
        double mean_s  = sum_s / nf,  mean_sp = sum_sp / nf;
        double var_d  = (sum_d2  - nf * mean_d  * mean_d)  / (nf - 1.0);
        double var_dp = (sum_dp2 - nf * mean_dp * mean_dp) / (nf - 1.0);
        double var_s  = (sum_s2  - nf * mean_s  * mean_s)  / (nf - 1.0);
        double var_sp = (sum_sp2 - nf * mean_sp * mean_sp) / (nf - 1.0);

        double dbp_mean_cost = fabs(mean_d - mean_dp) / mean_d;
        double sbp_mean_cost = fabs(mean_s - mean_sp) / mean_s;
        double dbp_var_cost  = fabs(var_d - var_dp) / var_d;
        double sbp_var_cost  = fabs(var_s - var_sp) / var_s;

        out[0] = (float)(rst_d + dbp_mean_cost + dbp_var_cost);
        out[1] = (float)(rst_s + sbp_mean_cost + sbp_var_cost);
        out[2] = (float)scale_cost;
    }
}

extern "C" void kernel_launch(void* const* d_in, const int* in_sizes, int n_in,
                              void* d_out, int out_size, void* d_ws, size_t ws_size,
                              hipStream_t stream) {
    const float* dp = (const float*)d_in[0];   // dbp_pred
    const float* sp = (const float*)d_in[1];   // sbp_pred
    // d_in[2] = mbp_pred (unused), d_in[5] = m (unused)
    const float* d  = (const float*)d_in[3];
    const float* s  = (const float*)d_in[4];
    const int n = in_sizes[0];

    double* partial = (double*)d_ws;           // NACC * GRID1 doubles = 384 KiB
    float* out = (float*)d_out;

    hipLaunchKernelGGL(amp_reduce, dim3(GRID1), dim3(256), 0, stream,
                       dp, sp, d, s, partial, n);
    hipLaunchKernelGGL(amp_final, dim3(1), dim3(1024), 0, stream,
                       partial, out, n);
}

// Round 6
// 32.872 us; speedup vs baseline: 1.4642x; 1.4351x over previous
//
#include <hip/hip_runtime.h>
#include <math.h>

#define NACC 24
#define GRID1 2048

// acc layout (canonical 24-vector):
//  0: lt count          (dbp_pred < sbp_pred)
//  1: sum_d   2: sum_d2   3: sum_dp  4: sum_dp2
//  5: sum_s   6: sum_s2   7: sum_sp  8: sum_sp2
//  9,12,15,18,21: mask counts
// 10,13,16,19,22: mask . smape_d
// 11,14,17,20,23: mask . smape_s

// f32 per-thread accumulation: 8 elements/thread -> ~1e-7 relative error,
// promoted to f64 before any cross-thread summation. Counts <= 8 are exact
// in f32.
__device__ __forceinline__ void process_elem(float* acc, int* cnt,
                                             float dpv, float spv, float dv, float sv) {
    cnt[0] += (dpv < spv) ? 1 : 0;
    acc[0] += dv;  acc[1] = fmaf(dv,  dv,  acc[1]);
    acc[2] += dpv; acc[3] = fmaf(dpv, dpv, acc[3]);
    acc[4] += sv;  acc[5] = fmaf(sv,  sv,  acc[5]);
    acc[6] += spv; acc[7] = fmaf(spv, spv, acc[7]);
    float smd = 2.0f * fabsf(dpv - dv) * __builtin_amdgcn_rcpf(fabsf(dpv) + fabsf(dv));
    float sms = 2.0f * fabsf(spv - sv) * __builtin_amdgcn_rcpf(fabsf(spv) + fabsf(sv));
    // mask precedence: & binds tighter than | in the reference
    bool m0 = (sv < 120.0f) && (dv < 80.0f);
    bool m1 = (sv >= 120.0f) && (sv < 130.0f) && (dv < 80.0f);
    bool m2 = ((sv >= 130.0f) && (sv < 140.0f)) || ((dv >= 80.0f) && (dv < 90.0f));
    bool m3 = (sv >= 140.0f) || (dv >= 90.0f);
    bool m4 = (sv > 180.0f) || (dv > 120.0f);
    cnt[1] += m0 ? 1 : 0;  acc[8]  += m0 ? smd : 0.0f;  acc[9]  += m0 ? sms : 0.0f;
    cnt[2] += m1 ? 1 : 0;  acc[10] += m1 ? smd : 0.0f;  acc[11] += m1 ? sms : 0.0f;
    cnt[3] += m2 ? 1 : 0;  acc[12] += m2 ? smd : 0.0f;  acc[13] += m2 ? sms : 0.0f;
    cnt[4] += m3 ? 1 : 0;  acc[14] += m3 ? smd : 0.0f;  acc[15] += m3 ? sms : 0.0f;
    cnt[5] += m4 ? 1 : 0;  acc[16] += m4 ? smd : 0.0f;  acc[17] += m4 ? sms : 0.0f;
}

__device__ __forceinline__ void process4(float* acc, int* cnt,
                                         float4 vdp, float4 vsp, float4 vd, float4 vs) {
    process_elem(acc, cnt, vdp.x, vsp.x, vd.x, vs.x);
    process_elem(acc, cnt, vdp.y, vsp.y, vd.y, vs.y);
    process_elem(acc, cnt, vdp.z, vsp.z, vd.z, vs.z);
    process_elem(acc, cnt, vdp.w, vsp.w, vd.w, vs.w);
}

// Block reduction via LDS store-then-gather (NO __shfl butterflies, NO atomics):
//   - each thread writes 24 f32 canonical values -> 24 ds_write_b32/wave
//     (vs 288 ds_bpermute for the f64 shuffle butterfly this replaces)
//   - 192 threads gather+sum 32 entries each (f64), bank-rotated
//   - 24 threads fold 8 partials -> per-block slot in global ws
__global__ __launch_bounds__(256) void amp_reduce(
    const float* __restrict__ dp, const float* __restrict__ sp,
    const float* __restrict__ d,  const float* __restrict__ s,
    double* __restrict__ partial, int n)
{
    __shared__ float  red[NACC][256];   // 24 KB
    __shared__ double red2[NACC][8];    // 1.5 KB

    const int tid = threadIdx.x;
    const int n4 = n >> 2;
    const int i0 = blockIdx.x * 512 + tid;   // float4 index, group 0
    const int i1 = i0 + 256;                 // float4 index, group 1

    const float4* dp4 = (const float4*)dp;
    const float4* sp4 = (const float4*)sp;
    const float4* d4  = (const float4*)d;
    const float4* s4  = (const float4*)s;

    const float4 z4 = make_float4(0.f, 0.f, 0.f, 0.f);
    const bool p0 = i0 < n4;
    const bool p1 = i1 < n4;

    // issue all 8 independent loads up front
    float4 a_dp0 = p0 ? dp4[i0] : z4;
    float4 a_sp0 = p0 ? sp4[i0] : z4;
    float4 a_d0  = p0 ? d4[i0]  : z4;
    float4 a_s0  = p0 ? s4[i0]  : z4;
    float4 a_dp1 = p1 ? dp4[i1] : z4;
    float4 a_sp1 = p1 ? sp4[i1] : z4;
    float4 a_d1  = p1 ? d4[i1]  : z4;
    float4 a_s1  = p1 ? s4[i1]  : z4;

    float accF[18];
    int   accI[6];
    #pragma unroll
    for (int k = 0; k < 18; ++k) accF[k] = 0.0f;
    #pragma unroll
    for (int k = 0; k < 6; ++k) accI[k] = 0;

    if (p0) process4(accF, accI, a_dp0, a_sp0, a_d0, a_s0);
    if (p1) process4(accF, accI, a_dp1, a_sp1, a_d1, a_s1);

    // canonical 24-vector in f32 (counts exact: <= 8)
    float can[NACC];
    can[0] = (float)accI[0];
    #pragma unroll
    for (int k = 0; k < 8; ++k) can[1 + k] = accF[k];
    #pragma unroll
    for (int g = 0; g < 5; ++g) {
        can[9 + 3 * g]  = (float)accI[1 + g];
        can[10 + 3 * g] = accF[8 + 2 * g];
        can[11 + 3 * g] = accF[9 + 2 * g];
    }

    #pragma unroll
    for (int k = 0; k < NACC; ++k) red[k][tid] = can[k];   // conflict-free
    __syncthreads();

    if (tid < 192) {
        const int k = tid >> 3;        // 0..23
        const int j = tid & 7;         // 0..7 : owns threads j*32..j*32+31
        const float* row = &red[k][j * 32];
        double s0 = 0.0, s1 = 0.0, s2 = 0.0, s3 = 0.0;
        #pragma unroll
        for (int i = 0; i < 32; i += 4) {
            // rotate by tid so the 64 lanes of a wave spread across banks
            s0 += (double)row[(i + 0 + tid) & 31];
            s1 += (double)row[(i + 1 + tid) & 31];
            s2 += (double)row[(i + 2 + tid) & 31];
            s3 += (double)row[(i + 3 + tid) & 31];
        }
        red2[k][j] = (s0 + s1) + (s2 + s3);
    }
    __syncthreads();

    if (tid < NACC) {
        double v = 0.0;
        #pragma unroll
        for (int j = 0; j < 8; ++j) v += red2[tid][j];
        // transposed layout: column k contiguous over blocks -> coalesced stage-2
        partial[tid * GRID1 + blockIdx.x] = v;
    }
}

// 1024 threads = 16 waves. Wave w reduces columns {w, w+16}; unrolled with
// 4 independent accumulators so loads pipeline.
__global__ __launch_bounds__(1024) void amp_final(
    const double* __restrict__ partial, float* __restrict__ out, int n)
{
    __shared__ double tot[NACC];
    const int lane = threadIdx.x & 63;
    const int wave = threadIdx.x >> 6;

    for (int k = wave; k < NACC; k += 16) {
        const double* col = partial + k * GRID1 + lane;
        double v0 = 0.0, v1 = 0.0, v2 = 0.0, v3 = 0.0;
        #pragma unroll
        for (int r = 0; r < GRID1 / 64; r += 4) {
            v0 += col[(r + 0) * 64];
            v1 += col[(r + 1) * 64];
            v2 += col[(r + 2) * 64];
            v3 += col[(r + 3) * 64];
        }
        double v = (v0 + v1) + (v2 + v3);
        #pragma unroll
        for (int off = 32; off > 0; off >>= 1)
            v += __shfl_down(v, off, 64);
        if (lane == 0) tot[k] = v;
    }
    __syncthreads();

    if (threadIdx.x == 0) {
        const double nf = (double)n;
        const double lt = tot[0];
        const double sum_d  = tot[1], sum_d2  = tot[2];
        const double sum_dp = tot[3], sum_dp2 = tot[4];
        const double sum_s  = tot[5], sum_s2  = tot[6];
        const double sum_sp = tot[7], sum_sp2 = tot[8];

        double scale_cost = 1.0 - lt / nf;

        double d_rst = 0.0, s_rst = 0.0, rst_d = 0.0, rst_s = 0.0;
        int cnt = 0;
        #pragma unroll
        for (int i = 0; i < 5; ++i) {
            double c   = tot[9 + 3 * i];
            double sdi = tot[10 + 3 * i];
            double ssi = tot[11 + 3 * i];
            double safe = fmax(c, 1.0);
            double w = sqrt(log(nf / safe));
            double sum_di = w * sdi;
            double sum_si = w * ssi;
            bool has = c > 0.0;
            double nd = (d_rst + sum_di) / safe;
            double ns = (s_rst + sum_si) / safe;
            if (has) {
                d_rst = nd; s_rst = ns;
                rst_d += nd; rst_s += ns;
                cnt++;
            }
        }
        double denom = (cnt == 0) ? 5.0 : (double)cnt;
        rst_d /= denom;
        rst_s /= denom;

        double mean_d  = sum_d / nf,  mean_dp = sum_dp / nf;
        double mean_s  = sum_s / nf,  mean_sp = sum_sp / nf;
        double var_d  = (sum_d2  - nf * mean_d  * mean_d)  / (nf - 1.0);
        double var_dp = (sum_dp2 - nf * mean_dp * mean_dp) / (nf - 1.0);
        double var_s  = (sum_s2  - nf * mean_s  * mean_s)  / (nf - 1.0);
        double var_sp = (sum_sp2 - nf * mean_sp * mean_sp) / (nf - 1.0);

        double dbp_mean_cost = fabs(mean_d - mean_dp) / mean_d;
        double sbp_mean_cost = fabs(mean_s - mean_sp) / mean_s;
        double dbp_var_cost  = fabs(var_d - var_dp) / var_d;
        double sbp_var_cost  = fabs(var_s - var_sp) / var_s;

        out[0] = (float)(rst_d + dbp_mean_cost + dbp_var_cost);
        out[1] = (float)(rst_s + sbp_mean_cost + sbp_var_cost);
        out[2] = (float)scale_cost;
    }
}

extern "C" void kernel_launch(void* const* d_in, const int* in_sizes, int n_in,
                              void* d_out, int out_size, void* d_ws, size_t ws_size,
                              hipStream_t stream) {
    const float* dp = (const float*)d_in[0];   // dbp_pred
    const float* sp = (const float*)d_in[1];   // sbp_pred
    // d_in[2] = mbp_pred (unused), d_in[5] = m (unused)
    const float* d  = (const float*)d_in[3];
    const float* s  = (const float*)d_in[4];
    const int n = in_sizes[0];

    double* partial = (double*)d_ws;           // NACC * GRID1 doubles = 384 KiB
    float* out = (float*)d_out;

    hipLaunchKernelGGL(amp_reduce, dim3(GRID1), dim3(256), 0, stream,
                       dp, sp, d, s, partial, n);
    hipLaunchKernelGGL(amp_final, dim3(1), dim3(1024), 0, stream,
                       partial, out, n);
}

// Round 7
// 30.889 us; speedup vs baseline: 1.5582x; 1.0642x over previous
//
#include <hip/hip_runtime.h>
#include <math.h>

#define NACC 24
#define GRID1 1024   // 1024 blocks x 256 thr x 16 elems = 4194304 exactly

// acc layout (canonical 24-vector):
//  0: lt count          (dbp_pred < sbp_pred)
//  1: sum_d   2: sum_d2   3: sum_dp  4: sum_dp2
//  5: sum_s   6: sum_s2   7: sum_sp  8: sum_sp2
//  9,12,15,18,21: mask counts
// 10,13,16,19,22: mask . smape_d
// 11,14,17,20,23: mask . smape_s

// f32 per-thread accumulation: 16 elements/thread -> ~2e-7 relative error,
// promoted to f64 before any cross-thread summation. Counts <= 16 exact in f32.
__device__ __forceinline__ void process_elem(float* acc, int* cnt,
                                             float dpv, float spv, float dv, float sv) {
    cnt[0] += (dpv < spv) ? 1 : 0;
    acc[0] += dv;  acc[1] = fmaf(dv,  dv,  acc[1]);
    acc[2] += dpv; acc[3] = fmaf(dpv, dpv, acc[3]);
    acc[4] += sv;  acc[5] = fmaf(sv,  sv,  acc[5]);
    acc[6] += spv; acc[7] = fmaf(spv, spv, acc[7]);
    float smd = 2.0f * fabsf(dpv - dv) * __builtin_amdgcn_rcpf(fabsf(dpv) + fabsf(dv));
    float sms = 2.0f * fabsf(spv - sv) * __builtin_amdgcn_rcpf(fabsf(spv) + fabsf(sv));
    // mask precedence: & binds tighter than | in the reference
    bool m0 = (sv < 120.0f) && (dv < 80.0f);
    bool m1 = (sv >= 120.0f) && (sv < 130.0f) && (dv < 80.0f);
    bool m2 = ((sv >= 130.0f) && (sv < 140.0f)) || ((dv >= 80.0f) && (dv < 90.0f));
    bool m3 = (sv >= 140.0f) || (dv >= 90.0f);
    bool m4 = (sv > 180.0f) || (dv > 120.0f);
    cnt[1] += m0 ? 1 : 0;  acc[8]  += m0 ? smd : 0.0f;  acc[9]  += m0 ? sms : 0.0f;
    cnt[2] += m1 ? 1 : 0;  acc[10] += m1 ? smd : 0.0f;  acc[11] += m1 ? sms : 0.0f;
    cnt[3] += m2 ? 1 : 0;  acc[12] += m2 ? smd : 0.0f;  acc[13] += m2 ? sms : 0.0f;
    cnt[4] += m3 ? 1 : 0;  acc[14] += m3 ? smd : 0.0f;  acc[15] += m3 ? sms : 0.0f;
    cnt[5] += m4 ? 1 : 0;  acc[16] += m4 ? smd : 0.0f;  acc[17] += m4 ? sms : 0.0f;
}

__device__ __forceinline__ void process4(float* acc, int* cnt,
                                         float4 vdp, float4 vsp, float4 vd, float4 vs) {
    process_elem(acc, cnt, vdp.x, vsp.x, vd.x, vs.x);
    process_elem(acc, cnt, vdp.y, vsp.y, vd.y, vs.y);
    process_elem(acc, cnt, vdp.z, vsp.z, vd.z, vs.z);
    process_elem(acc, cnt, vdp.w, vsp.w, vd.w, vs.w);
}

// launch_bounds(256, 4): cap at 4 waves/EU -> <=128 VGPR, so the 16 staged
// float4s (64 VGPR) can genuinely be register-resident and all 16 loads stay
// in flight. Without this the allocator targets 8 waves/EU (64 VGPR) and
// re-serializes the loads (rounds 3-5 all plateaued at ~43 us because of it).
__global__ __launch_bounds__(256, 4) void amp_reduce(
    const float* __restrict__ dp, const float* __restrict__ sp,
    const float* __restrict__ d,  const float* __restrict__ s,
    double* __restrict__ partial, int n)
{
    __shared__ float  red[NACC][256];   // 24 KB
    __shared__ double red2[NACC][8];    // 1.5 KB

    const int tid  = threadIdx.x;
    const int n4   = n >> 2;
    const int gtid = blockIdx.x * 256 + tid;
    const int S    = GRID1 * 256;       // float4 stride between tiles

    const float4* dp4 = (const float4*)dp;
    const float4* sp4 = (const float4*)sp;
    const float4* d4  = (const float4*)d;
    const float4* s4  = (const float4*)s;

    const float4 z4 = make_float4(0.f, 0.f, 0.f, 0.f);

    // stage ALL 16 independent loads into registers before any use
    float4 vdp[4], vsp[4], vd[4], vs[4];
    #pragma unroll
    for (int t = 0; t < 4; ++t) {
        const int i = gtid + t * S;
        const bool p = i < n4;          // exact fit for N=4194304; guard kept
        vdp[t] = p ? dp4[i] : z4;
        vsp[t] = p ? sp4[i] : z4;
        vd[t]  = p ? d4[i]  : z4;
        vs[t]  = p ? s4[i]  : z4;
    }

    float accF[18];
    int   accI[6];
    #pragma unroll
    for (int k = 0; k < 18; ++k) accF[k] = 0.0f;
    #pragma unroll
    for (int k = 0; k < 6; ++k) accI[k] = 0;

    #pragma unroll
    for (int t = 0; t < 4; ++t)
        process4(accF, accI, vdp[t], vsp[t], vd[t], vs[t]);

    // canonical 24-vector in f32 (counts exact: <= 16)
    float can[NACC];
    can[0] = (float)accI[0];
    #pragma unroll
    for (int k = 0; k < 8; ++k) can[1 + k] = accF[k];
    #pragma unroll
    for (int g = 0; g < 5; ++g) {
        can[9 + 3 * g]  = (float)accI[1 + g];
        can[10 + 3 * g] = accF[8 + 2 * g];
        can[11 + 3 * g] = accF[9 + 2 * g];
    }

    // block reduction via LDS store-then-gather (no shuffles, no atomics)
    #pragma unroll
    for (int k = 0; k < NACC; ++k) red[k][tid] = can[k];   // conflict-free
    __syncthreads();

    if (tid < 192) {
        const int k = tid >> 3;        // 0..23
        const int j = tid & 7;         // 0..7 : owns threads j*32..j*32+31
        const float* row = &red[k][j * 32];
        double s0 = 0.0, s1 = 0.0, s2 = 0.0, s3 = 0.0;
        #pragma unroll
        for (int i = 0; i < 32; i += 4) {
            s0 += (double)row[(i + 0 + tid) & 31];
            s1 += (double)row[(i + 1 + tid) & 31];
            s2 += (double)row[(i + 2 + tid) & 31];
            s3 += (double)row[(i + 3 + tid) & 31];
        }
        red2[k][j] = (s0 + s1) + (s2 + s3);
    }
    __syncthreads();

    if (tid < NACC) {
        double v = 0.0;
        #pragma unroll
        for (int j = 0; j < 8; ++j) v += red2[tid][j];
        // transposed layout: column k contiguous over blocks -> coalesced stage-2
        partial[tid * GRID1 + blockIdx.x] = v;
    }
}

// 1024 threads = 16 waves. Wave w reduces columns {w, w+16}; unrolled with
// 4 independent accumulators so loads pipeline.
__global__ __launch_bounds__(1024) void amp_final(
    const double* __restrict__ partial, float* __restrict__ out, int n)
{
    __shared__ double tot[NACC];
    const int lane = threadIdx.x & 63;
    const int wave = threadIdx.x >> 6;

    for (int k = wave; k < NACC; k += 16) {
        const double* col = partial + k * GRID1 + lane;
        double v0 = 0.0, v1 = 0.0, v2 = 0.0, v3 = 0.0;
        #pragma unroll
        for (int r = 0; r < GRID1 / 64; r += 4) {
            v0 += col[(r + 0) * 64];
            v1 += col[(r + 1) * 64];
            v2 += col[(r + 2) * 64];
            v3 += col[(r + 3) * 64];
        }
        double v = (v0 + v1) + (v2 + v3);
        #pragma unroll
        for (int off = 32; off > 0; off >>= 1)
            v += __shfl_down(v, off, 64);
        if (lane == 0) tot[k] = v;
    }
    __syncthreads();

    if (threadIdx.x == 0) {
        const double nf = (double)n;
        const double lt = tot[0];
        const double sum_d  = tot[1], sum_d2  = tot[2];
        const double sum_dp = tot[3], sum_dp2 = tot[4];
        const double sum_s  = tot[5], sum_s2  = tot[6];
        const double sum_sp = tot[7], sum_sp2 = tot[8];

        double scale_cost = 1.0 - lt / nf;

        double d_rst = 0.0, s_rst = 0.0, rst_d = 0.0, rst_s = 0.0;
        int cnt = 0;
        #pragma unroll
        for (int i = 0; i < 5; ++i) {
            double c   = tot[9 + 3 * i];
            double sdi = tot[10 + 3 * i];
            double ssi = tot[11 + 3 * i];
            double safe = fmax(c, 1.0);
            double w = sqrt(log(nf / safe));
            double sum_di = w * sdi;
            double sum_si = w * ssi;
            bool has = c > 0.0;
            double nd = (d_rst + sum_di) / safe;
            double ns = (s_rst + sum_si) / safe;
            if (has) {
                d_rst = nd; s_rst = ns;
                rst_d += nd; rst_s += ns;
                cnt++;
            }
        }
        double denom = (cnt == 0) ? 5.0 : (double)cnt;
        rst_d /= denom;
        rst_s /= denom;

        double mean_d  = sum_d / nf,  mean_dp = sum_dp / nf;
        double mean_s  = sum_s / nf,  mean_sp = sum_sp / nf;
        double var_d  = (sum_d2  - nf * mean_d  * mean_d)  / (nf - 1.0);
        double var_dp = (sum_dp2 - nf * mean_dp * mean_dp) / (nf - 1.0);
        double var_s  = (sum_s2  - nf * mean_s  * mean_s)  / (nf - 1.0);
        double var_sp = (sum_sp2 - nf * mean_sp * mean_sp) / (nf - 1.0);

        double dbp_mean_cost = fabs(mean_d - mean_dp) / mean_d;
        double sbp_mean_cost = fabs(mean_s - mean_sp) / mean_s;
        double dbp_var_cost  = fabs(var_d - var_dp) / var_d;
        double sbp_var_cost  = fabs(var_s - var_sp) / var_s;

        out[0] = (float)(rst_d + dbp_mean_cost + dbp_var_cost);
        out[1] = (float)(rst_s + sbp_mean_cost + sbp_var_cost);
        out[2] = (float)scale_cost;
    }
}

extern "C" void kernel_launch(void* const* d_in, const int* in_sizes, int n_in,
                              void* d_out, int out_size, void* d_ws, size_t ws_size,
                              hipStream_t stream) {
    const float* dp = (const float*)d_in[0];   // dbp_pred
    const float* sp = (const float*)d_in[1];   // sbp_pred
    // d_in[2] = mbp_pred (unused), d_in[5] = m (unused)
    const float* d  = (const float*)d_in[3];
    const float* s  = (const float*)d_in[4];
    const int n = in_sizes[0];

    double* partial = (double*)d_ws;           // NACC * GRID1 doubles = 192 KiB
    float* out = (float*)d_out;

    hipLaunchKernelGGL(amp_reduce, dim3(GRID1), dim3(256), 0, stream,
                       dp, sp, d, s, partial, n);
    hipLaunchKernelGGL(amp_final, dim3(1), dim3(1024), 0, stream,
                       partial, out, n);
}